// Round 1
// baseline (1308.457 us; speedup 1.0000x reference)
//
#include <hip/hip_runtime.h>

// Problem constants (fixed by setup_inputs)
#define NNODES 8000
#define NEDGES 192000
#define NREL   65
#define RP     66      // +1 pseudo-relation for the root/self term
#define HDIM   256
#define FDIM   64
#define NGRAPH 128
#define MDIM   64
#define TILE_M 64
#define MAXT   3456    // >= E/64 + RP + N/64 = 3190

typedef _Float16 half8 __attribute__((ext_vector_type(8)));
typedef float    f32x4 __attribute__((ext_vector_type(4)));

// ---------------- setup kernels ----------------

__global__ void count_kernel(const int* __restrict__ ei, const int* __restrict__ et,
                             int* __restrict__ cnt_rn, int* __restrict__ type_cnt) {
    int e = blockIdx.x * 256 + threadIdx.x;
    if (e < NEDGES) {
        int t = et[e];
        atomicAdd(&type_cnt[t], 1);
        atomicAdd(&cnt_rn[t * NNODES + ei[NEDGES + e]], 1);
    }
}

__global__ void scan_tiles_kernel(const int* __restrict__ type_cnt, int* __restrict__ type_off,
                                  int* __restrict__ tile_rel, int* __restrict__ tile_start,
                                  int* __restrict__ tile_nrows) {
    __shared__ int s_off[RP + 1];
    __shared__ int s_toff[RP + 1];
    if (threadIdx.x == 0) {
        int off = 0, toff = 0;
        for (int r = 0; r < RP; r++) {
            int c = (r < NREL) ? type_cnt[r] : NNODES;
            s_off[r] = off; s_toff[r] = toff;
            off += c; toff += (c + TILE_M - 1) / TILE_M;
        }
        s_off[RP] = off; s_toff[RP] = toff;
        type_off[RP] = off;
    }
    __syncthreads();
    int r = threadIdx.x;
    if (r < RP) {
        type_off[r] = s_off[r];
        int c = s_off[r + 1] - s_off[r];
        int nt = (c + TILE_M - 1) / TILE_M;
        for (int i = 0; i < nt; i++) {
            int idx = s_toff[r] + i;
            tile_rel[idx]   = r;
            tile_start[idx] = s_off[r] + i * TILE_M;
            tile_nrows[idx] = min(TILE_M, c - i * TILE_M);
        }
    }
}

__global__ void scatter_kernel(const int* __restrict__ ei, const int* __restrict__ et,
                               const int* __restrict__ cnt_rn, const int* __restrict__ type_off,
                               int* __restrict__ type_cur,
                               int* __restrict__ esrc, int* __restrict__ edst,
                               float* __restrict__ escale) {
    int i = blockIdx.x * 256 + threadIdx.x;
    if (i < NEDGES) {
        int t = et[i];
        int p = type_off[t] + atomicAdd(&type_cur[t], 1);
        int d = ei[NEDGES + i];
        esrc[p] = ei[i];
        edst[p] = d;
        escale[p] = 1.0f / (float)cnt_rn[t * NNODES + d];
    } else if (i < NEDGES + NNODES) {
        int n = i - NEDGES;
        int p = NEDGES + n;      // root pseudo-relation segment starts at E
        esrc[p] = n; edst[p] = n; escale[p] = 1.0f;
    }
}

// W [R][K][HDIM] fp32 (+ root [K][HDIM]) -> Wt [RP][HDIM][K] fp16 (transposed)
__global__ void convW_kernel(const float* __restrict__ W, const float* __restrict__ root,
                             _Float16* __restrict__ Wt, int K) {
    int r = blockIdx.x, k0 = blockIdx.y * 32, n0 = blockIdx.z * 32;
    const float* src = (r < NREL) ? (W + (size_t)r * K * HDIM) : root;
    __shared__ float tile[32][33];
    int tj = threadIdx.x & 31, ti = threadIdx.x >> 5;
    #pragma unroll
    for (int s = 0; s < 4; s++) {
        int i = ti + s * 8;
        tile[i][tj] = src[(size_t)(k0 + i) * HDIM + n0 + tj];
    }
    __syncthreads();
    #pragma unroll
    for (int s = 0; s < 4; s++) {
        int i = ti + s * 8;
        Wt[((size_t)r * HDIM + (n0 + i)) * K + k0 + tj] = (_Float16)tile[tj][i];
    }
}

__global__ void conv_x_kernel(const float* __restrict__ x, _Float16* __restrict__ x16) {
    int i = blockIdx.x * 256 + threadIdx.x;
    if (i < NNODES * FDIM) x16[i] = (_Float16)x[i];
}

__global__ void bias_init_kernel(const float* __restrict__ b, float* __restrict__ out) {
    int i = blockIdx.x * 256 + threadIdx.x;
    if (i < NNODES * HDIM) out[i] = b[i & (HDIM - 1)];
}

__global__ void relu_kernel(float* __restrict__ h, _Float16* __restrict__ h16) {
    int i = blockIdx.x * 256 + threadIdx.x;
    if (i < NNODES * HDIM) {
        float v = h[i];
        v = v > 0.f ? v : 0.f;
        h[i] = v;
        h16[i] = (_Float16)v;
    }
}

// ---------------- edge GEMM: out[dst] += scale * (h[src] @ W_r) ----------------
// Tile: 64 edges x 256 cols. 4 waves; wave w owns cols [w*64, w*64+64).
// A staged in LDS (fp16, padded); B read from Wt[r][n][k] (fp16, k contiguous).
template <int K>
__global__ __launch_bounds__(256)
void edge_gemm_kernel(const _Float16* __restrict__ hin, const _Float16* __restrict__ Wt,
                      const int* __restrict__ esrc, const int* __restrict__ edst,
                      const float* __restrict__ escale,
                      const int* __restrict__ tile_rel, const int* __restrict__ tile_start,
                      const int* __restrict__ tile_nrows,
                      float* __restrict__ out) {
    int nr = tile_nrows[blockIdx.x];
    if (nr == 0) return;
    int r  = tile_rel[blockIdx.x];
    int ts = tile_start[blockIdx.x];

    constexpr int LK = K + 8;           // +8 fp16 pad -> rows advance 4 banks
    __shared__ _Float16 sA[TILE_M * LK];
    __shared__ int   sdst[TILE_M];
    __shared__ float sscale[TILE_M];

    int tid = threadIdx.x;
    constexpr int CPR = K / 8;          // 16B chunks per row
    for (int idx = tid; idx < TILE_M * CPR; idx += 256) {
        int row = idx / CPR, c = idx % CPR;
        uint4 v = make_uint4(0, 0, 0, 0);
        if (row < nr) {
            int src = esrc[ts + row];
            v = *(const uint4*)(hin + (size_t)src * K + c * 8);
        }
        *(uint4*)&sA[row * LK + c * 8] = v;
    }
    if (tid < TILE_M) {
        if (tid < nr) { sdst[tid] = edst[ts + tid]; sscale[tid] = escale[ts + tid]; }
        else          { sdst[tid] = 0;              sscale[tid] = 0.f; }
    }
    __syncthreads();

    int lane = tid & 63, w = tid >> 6;
    int lm = lane & 15, quad = lane >> 4;
    f32x4 acc[4][4] = {};
    const _Float16* Bbase = Wt + ((size_t)r * HDIM + w * 64 + lm) * K + quad * 8;
    const _Float16* Abase = sA + lm * LK + quad * 8;

    for (int kk = 0; kk < K; kk += 32) {
        half8 a[4], b[4];
        #pragma unroll
        for (int mt = 0; mt < 4; mt++)
            a[mt] = *(const half8*)(Abase + mt * 16 * LK + kk);
        #pragma unroll
        for (int nt = 0; nt < 4; nt++)
            b[nt] = *(const half8*)(Bbase + nt * 16 * K + kk);
        #pragma unroll
        for (int mt = 0; mt < 4; mt++)
            #pragma unroll
            for (int nt = 0; nt < 4; nt++)
                acc[mt][nt] = __builtin_amdgcn_mfma_f32_16x16x32_f16(a[mt], b[nt], acc[mt][nt], 0, 0, 0);
    }

    // D[m][n]: m = mt*16 + quad*4 + rr, n = w*64 + nt*16 + lm
    #pragma unroll
    for (int mt = 0; mt < 4; mt++) {
        #pragma unroll
        for (int rr = 0; rr < 4; rr++) {
            int row = mt * 16 + quad * 4 + rr;
            if (row < nr) {
                float s = sscale[row];
                int d = sdst[row];
                #pragma unroll
                for (int nt = 0; nt < 4; nt++) {
                    int col = w * 64 + nt * 16 + lm;
                    atomicAdd(&out[(size_t)d * HDIM + col], acc[mt][nt][rr] * s);
                }
            }
        }
    }
}

// ---------------- pooling + head ----------------

__global__ void pool_kernel(const float* __restrict__ h, const int* __restrict__ batch,
                            const float* __restrict__ ws_w, const float* __restrict__ ws_b,
                            float* __restrict__ pooled) {
    int n = blockIdx.x, tid = threadIdx.x;
    float v = h[(size_t)n * HDIM + tid];
    float p = v * ws_w[tid];
    __shared__ float red[4];
    __shared__ float gate;
    for (int o = 32; o > 0; o >>= 1) p += __shfl_down(p, o, 64);
    if ((tid & 63) == 0) red[tid >> 6] = p;
    __syncthreads();
    if (tid == 0) {
        float s = red[0] + red[1] + red[2] + red[3] + ws_b[0];
        gate = 1.f / (1.f + __expf(-s));
    }
    __syncthreads();
    atomicAdd(&pooled[(size_t)batch[n] * HDIM + tid], gate * v);
}

__global__ void head_kernel(const float* __restrict__ pooled,
                            const float* __restrict__ w1, const float* __restrict__ b1,
                            const float* __restrict__ w2, const float* __restrict__ b2,
                            const float* __restrict__ w3, const float* __restrict__ b3,
                            float* __restrict__ out) {
    int b = blockIdx.x, tid = threadIdx.x;   // 64 threads = 1 wave
    __shared__ float sp[HDIM];
    __shared__ float m1[MDIM];
    __shared__ float m2[MDIM];
    for (int i = tid; i < HDIM; i += 64) sp[i] = pooled[(size_t)b * HDIM + i];
    __syncthreads();
    float a = b1[tid];
    for (int i = 0; i < HDIM; i++) a += sp[i] * w1[i * MDIM + tid];
    m1[tid] = a > 0.f ? a : 0.f;
    __syncthreads();
    float c = b2[tid];
    for (int i = 0; i < MDIM; i++) c += m1[i] * w2[i * MDIM + tid];
    m2[tid] = c > 0.f ? c : 0.f;
    __syncthreads();
    float p = m2[tid] * w3[tid];
    for (int o = 32; o > 0; o >>= 1) p += __shfl_down(p, o, 64);
    if (tid == 0) out[b] = p + b3[0];
}

// ---------------- launch ----------------

extern "C" void kernel_launch(void* const* d_in, const int* in_sizes, int n_in,
                              void* d_out, int out_size, void* d_ws, size_t ws_size,
                              hipStream_t stream) {
    const float* x     = (const float*)d_in[0];
    const int*   ei    = (const int*)d_in[1];
    const int*   et    = (const int*)d_in[2];
    const int*   batch = (const int*)d_in[3];
    const float* W1    = (const float*)d_in[4];
    const float* root1 = (const float*)d_in[5];
    const float* b1    = (const float*)d_in[6];
    const float* W2    = (const float*)d_in[7];
    const float* root2 = (const float*)d_in[8];
    const float* b2    = (const float*)d_in[9];
    const float* W3    = (const float*)d_in[10];
    const float* root3 = (const float*)d_in[11];
    const float* b3    = (const float*)d_in[12];
    const float* ws_w  = (const float*)d_in[13];
    const float* ws_b  = (const float*)d_in[14];
    const float* m_w1  = (const float*)d_in[15];
    const float* m_b1  = (const float*)d_in[16];
    const float* m_w2  = (const float*)d_in[17];
    const float* m_b2  = (const float*)d_in[18];
    const float* m_w3  = (const float*)d_in[19];
    const float* m_b3  = (const float*)d_in[20];
    float* out = (float*)d_out;

    char* ws = (char*)d_ws;
    size_t o = 0;
    auto take = [&](size_t bytes) { size_t r = o; o = (o + bytes + 255) & ~(size_t)255; return r; };

    const int EP = NEDGES + NNODES;     // edges incl. root pseudo-edges
    size_t o_cnt_rn = take((size_t)NREL * NNODES * 4);
    size_t o_tcnt   = take(RP * 4);
    size_t o_tcur   = take(RP * 4);
    size_t o_toff   = take((RP + 1) * 4);
    size_t o_esrc   = take((size_t)EP * 4);
    size_t o_edst   = take((size_t)EP * 4);
    size_t o_escale = take((size_t)EP * 4);
    size_t o_trel   = take(MAXT * 4);
    size_t o_tstart = take(MAXT * 4);
    size_t o_tnrows = take(MAXT * 4);
    size_t o_wt1    = take((size_t)RP * HDIM * FDIM * 2);
    size_t o_wt2    = take((size_t)RP * HDIM * HDIM * 2);
    size_t o_wt3    = take((size_t)RP * HDIM * HDIM * 2);
    size_t o_x16    = take((size_t)NNODES * FDIM * 2);
    size_t o_h16    = take((size_t)NNODES * HDIM * 2);
    size_t o_hf32   = take((size_t)NNODES * HDIM * 4);
    size_t o_pool   = take((size_t)NGRAPH * HDIM * 4);

    int*      cnt_rn   = (int*)(ws + o_cnt_rn);
    int*      type_cnt = (int*)(ws + o_tcnt);
    int*      type_cur = (int*)(ws + o_tcur);
    int*      type_off = (int*)(ws + o_toff);
    int*      esrc     = (int*)(ws + o_esrc);
    int*      edst     = (int*)(ws + o_edst);
    float*    escale   = (float*)(ws + o_escale);
    int*      trel     = (int*)(ws + o_trel);
    int*      tstart   = (int*)(ws + o_tstart);
    int*      tnrows   = (int*)(ws + o_tnrows);
    _Float16* Wt1      = (_Float16*)(ws + o_wt1);
    _Float16* Wt2      = (_Float16*)(ws + o_wt2);
    _Float16* Wt3      = (_Float16*)(ws + o_wt3);
    _Float16* x16      = (_Float16*)(ws + o_x16);
    _Float16* h16      = (_Float16*)(ws + o_h16);
    float*    hf32     = (float*)(ws + o_hf32);
    float*    pooled   = (float*)(ws + o_pool);

    // zero: cnt_rn + type_cnt + type_cur (contiguous), tile_nrows, pooled
    hipMemsetAsync(ws + o_cnt_rn, 0, o_toff - o_cnt_rn, stream);
    hipMemsetAsync(ws + o_tnrows, 0, MAXT * 4, stream);
    hipMemsetAsync(ws + o_pool, 0, (size_t)NGRAPH * HDIM * 4, stream);

    count_kernel<<<(NEDGES + 255) / 256, 256, 0, stream>>>(ei, et, cnt_rn, type_cnt);
    scan_tiles_kernel<<<1, 128, 0, stream>>>(type_cnt, type_off, trel, tstart, tnrows);
    scatter_kernel<<<(EP + 255) / 256, 256, 0, stream>>>(ei, et, cnt_rn, type_off, type_cur,
                                                         esrc, edst, escale);

    convW_kernel<<<dim3(RP, FDIM / 32, HDIM / 32), 256, 0, stream>>>(W1, root1, Wt1, FDIM);
    convW_kernel<<<dim3(RP, HDIM / 32, HDIM / 32), 256, 0, stream>>>(W2, root2, Wt2, HDIM);
    convW_kernel<<<dim3(RP, HDIM / 32, HDIM / 32), 256, 0, stream>>>(W3, root3, Wt3, HDIM);
    conv_x_kernel<<<(NNODES * FDIM + 255) / 256, 256, 0, stream>>>(x, x16);

    const int NH_BLK = (NNODES * HDIM + 255) / 256;

    // Layer 1 (K=64)
    bias_init_kernel<<<NH_BLK, 256, 0, stream>>>(b1, hf32);
    edge_gemm_kernel<FDIM><<<MAXT, 256, 0, stream>>>(x16, Wt1, esrc, edst, escale,
                                                     trel, tstart, tnrows, hf32);
    relu_kernel<<<NH_BLK, 256, 0, stream>>>(hf32, h16);

    // Layer 2 (K=256)
    bias_init_kernel<<<NH_BLK, 256, 0, stream>>>(b2, hf32);
    edge_gemm_kernel<HDIM><<<MAXT, 256, 0, stream>>>(h16, Wt2, esrc, edst, escale,
                                                     trel, tstart, tnrows, hf32);
    relu_kernel<<<NH_BLK, 256, 0, stream>>>(hf32, h16);

    // Layer 3 (K=256)
    bias_init_kernel<<<NH_BLK, 256, 0, stream>>>(b3, hf32);
    edge_gemm_kernel<HDIM><<<MAXT, 256, 0, stream>>>(h16, Wt3, esrc, edst, escale,
                                                     trel, tstart, tnrows, hf32);
    relu_kernel<<<NH_BLK, 256, 0, stream>>>(hf32, h16);

    pool_kernel<<<NNODES, 256, 0, stream>>>(hf32, batch, ws_w, ws_b, pooled);
    head_kernel<<<NGRAPH, 64, 0, stream>>>(pooled, m_w1, m_b1, m_w2, m_b2, m_w3, m_b3, out);

    (void)in_sizes; (void)n_in; (void)out_size; (void)ws_size;
}

// Round 2
// 769.453 us; speedup vs baseline: 1.7005x; 1.7005x over previous
//
#include <hip/hip_runtime.h>

// Problem constants (fixed by setup_inputs)
#define NNODES 8000
#define NEDGES 192000
#define NREL   65
#define RP     66      // +1 pseudo-relation for the root/self term
#define HDIM   256
#define FDIM   64
#define NGRAPH 128
#define MDIM   64
#define TILE_M 64
#define MAXT   3456    // >= E/64 + RP + N/64 = 3190

typedef _Float16 half8 __attribute__((ext_vector_type(8)));
typedef float    f32x4 __attribute__((ext_vector_type(4)));

// ---------------- setup kernels ----------------

// R1 lesson: 192K global atomics onto 65 addresses = 292 us of serialization.
// Block-local LDS histogram first, then <=65 global atomics per block.
__global__ void count_kernel(const int* __restrict__ ei, const int* __restrict__ et,
                             int* __restrict__ cnt_rn, int* __restrict__ type_cnt) {
    __shared__ int lbin[NREL];
    int tid = threadIdx.x;
    if (tid < NREL) lbin[tid] = 0;
    __syncthreads();
    int e = blockIdx.x * 256 + tid;
    if (e < NEDGES) {
        int t = et[e];
        atomicAdd(&lbin[t], 1);                              // LDS atomic: cheap
        atomicAdd(&cnt_rn[t * NNODES + ei[NEDGES + e]], 1);  // 520K addrs: low contention
    }
    __syncthreads();
    if (tid < NREL && lbin[tid] > 0) atomicAdd(&type_cnt[tid], lbin[tid]);
}

__global__ void scan_tiles_kernel(const int* __restrict__ type_cnt, int* __restrict__ type_off,
                                  int* __restrict__ tile_rel, int* __restrict__ tile_start,
                                  int* __restrict__ tile_nrows) {
    __shared__ int s_off[RP + 1];
    __shared__ int s_toff[RP + 1];
    if (threadIdx.x == 0) {
        int off = 0, toff = 0;
        for (int r = 0; r < RP; r++) {
            int c = (r < NREL) ? type_cnt[r] : NNODES;
            s_off[r] = off; s_toff[r] = toff;
            off += c; toff += (c + TILE_M - 1) / TILE_M;
        }
        s_off[RP] = off; s_toff[RP] = toff;
        type_off[RP] = off;
    }
    __syncthreads();
    int r = threadIdx.x;
    if (r < RP) {
        type_off[r] = s_off[r];
        int c = s_off[r + 1] - s_off[r];
        int nt = (c + TILE_M - 1) / TILE_M;
        for (int i = 0; i < nt; i++) {
            int idx = s_toff[r] + i;
            tile_rel[idx]   = r;
            tile_start[idx] = s_off[r] + i * TILE_M;
            tile_nrows[idx] = min(TILE_M, c - i * TILE_M);
        }
    }
}

// Block-aggregated rank assignment: LDS atomic gives within-block rank,
// one global atomic per (block, type) gives the base.
__global__ void scatter_kernel(const int* __restrict__ ei, const int* __restrict__ et,
                               const int* __restrict__ cnt_rn, const int* __restrict__ type_off,
                               int* __restrict__ type_cur,
                               int* __restrict__ esrc, int* __restrict__ edst,
                               float* __restrict__ escale) {
    __shared__ int lbin[NREL];
    __shared__ int gbase[NREL];
    int tid = threadIdx.x;
    if (tid < NREL) lbin[tid] = 0;
    __syncthreads();
    int i = blockIdx.x * 256 + tid;
    int t = 0, lrank = 0;
    bool is_edge = (i < NEDGES);
    if (is_edge) {
        t = et[i];
        lrank = atomicAdd(&lbin[t], 1);
    }
    __syncthreads();
    if (tid < NREL && lbin[tid] > 0) gbase[tid] = atomicAdd(&type_cur[tid], lbin[tid]);
    __syncthreads();
    if (is_edge) {
        int d = ei[NEDGES + i];
        int p = type_off[t] + gbase[t] + lrank;
        esrc[p] = ei[i];
        edst[p] = d;
        escale[p] = 1.0f / (float)cnt_rn[t * NNODES + d];
    } else if (i < NEDGES + NNODES) {
        int n = i - NEDGES;
        int p = NEDGES + n;      // root pseudo-relation segment starts at E
        esrc[p] = n; edst[p] = n; escale[p] = 1.0f;
    }
}

// W [R][K][HDIM] fp32 (+ root [K][HDIM]) -> Wt [RP][HDIM][K] fp16 (transposed)
__global__ void convW_kernel(const float* __restrict__ W, const float* __restrict__ root,
                             _Float16* __restrict__ Wt, int K) {
    int r = blockIdx.x, k0 = blockIdx.y * 32, n0 = blockIdx.z * 32;
    const float* src = (r < NREL) ? (W + (size_t)r * K * HDIM) : root;
    __shared__ float tile[32][33];
    int tj = threadIdx.x & 31, ti = threadIdx.x >> 5;
    #pragma unroll
    for (int s = 0; s < 4; s++) {
        int i = ti + s * 8;
        tile[i][tj] = src[(size_t)(k0 + i) * HDIM + n0 + tj];
    }
    __syncthreads();
    #pragma unroll
    for (int s = 0; s < 4; s++) {
        int i = ti + s * 8;
        Wt[((size_t)r * HDIM + (n0 + i)) * K + k0 + tj] = (_Float16)tile[tj][i];
    }
}

__global__ void conv_x_kernel(const float* __restrict__ x, _Float16* __restrict__ x16) {
    int i = blockIdx.x * 256 + threadIdx.x;
    if (i < NNODES * FDIM) x16[i] = (_Float16)x[i];
}

__global__ void bias_init_kernel(const float* __restrict__ b, float* __restrict__ out) {
    int i = blockIdx.x * 256 + threadIdx.x;
    if (i < NNODES * HDIM) out[i] = b[i & (HDIM - 1)];
}

__global__ void relu_kernel(float* __restrict__ h, _Float16* __restrict__ h16) {
    int i = blockIdx.x * 256 + threadIdx.x;
    if (i < NNODES * HDIM) {
        float v = h[i];
        v = v > 0.f ? v : 0.f;
        h[i] = v;
        h16[i] = (_Float16)v;
    }
}

// ---------------- edge GEMM: out[dst] += scale * (h[src] @ W_r) ----------------
// Tile: 64 edges x 256 cols. 4 waves; wave w owns cols [w*64, w*64+64).
// A staged in LDS (fp16, padded); B read from Wt[r][n][k] (fp16, k contiguous).
template <int K>
__global__ __launch_bounds__(256)
void edge_gemm_kernel(const _Float16* __restrict__ hin, const _Float16* __restrict__ Wt,
                      const int* __restrict__ esrc, const int* __restrict__ edst,
                      const float* __restrict__ escale,
                      const int* __restrict__ tile_rel, const int* __restrict__ tile_start,
                      const int* __restrict__ tile_nrows,
                      float* __restrict__ out) {
    int nr = tile_nrows[blockIdx.x];
    if (nr == 0) return;
    int r  = tile_rel[blockIdx.x];
    int ts = tile_start[blockIdx.x];

    constexpr int LK = K + 8;           // +8 fp16 pad -> rows advance 4 banks
    __shared__ _Float16 sA[TILE_M * LK];
    __shared__ int   sdst[TILE_M];
    __shared__ float sscale[TILE_M];

    int tid = threadIdx.x;
    constexpr int CPR = K / 8;          // 16B chunks per row
    for (int idx = tid; idx < TILE_M * CPR; idx += 256) {
        int row = idx / CPR, c = idx % CPR;
        uint4 v = make_uint4(0, 0, 0, 0);
        if (row < nr) {
            int src = esrc[ts + row];
            v = *(const uint4*)(hin + (size_t)src * K + c * 8);
        }
        *(uint4*)&sA[row * LK + c * 8] = v;
    }
    if (tid < TILE_M) {
        if (tid < nr) { sdst[tid] = edst[ts + tid]; sscale[tid] = escale[ts + tid]; }
        else          { sdst[tid] = 0;              sscale[tid] = 0.f; }
    }
    __syncthreads();

    int lane = tid & 63, w = tid >> 6;
    int lm = lane & 15, quad = lane >> 4;
    f32x4 acc[4][4] = {};
    const _Float16* Bbase = Wt + ((size_t)r * HDIM + w * 64 + lm) * K + quad * 8;
    const _Float16* Abase = sA + lm * LK + quad * 8;

    for (int kk = 0; kk < K; kk += 32) {
        half8 a[4], b[4];
        #pragma unroll
        for (int mt = 0; mt < 4; mt++)
            a[mt] = *(const half8*)(Abase + mt * 16 * LK + kk);
        #pragma unroll
        for (int nt = 0; nt < 4; nt++)
            b[nt] = *(const half8*)(Bbase + nt * 16 * K + kk);
        #pragma unroll
        for (int mt = 0; mt < 4; mt++)
            #pragma unroll
            for (int nt = 0; nt < 4; nt++)
                acc[mt][nt] = __builtin_amdgcn_mfma_f32_16x16x32_f16(a[mt], b[nt], acc[mt][nt], 0, 0, 0);
    }

    // D[m][n]: m = mt*16 + quad*4 + rr, n = w*64 + nt*16 + lm
    #pragma unroll
    for (int mt = 0; mt < 4; mt++) {
        #pragma unroll
        for (int rr = 0; rr < 4; rr++) {
            int row = mt * 16 + quad * 4 + rr;
            if (row < nr) {
                float s = sscale[row];
                int d = sdst[row];
                #pragma unroll
                for (int nt = 0; nt < 4; nt++) {
                    int col = w * 64 + nt * 16 + lm;
                    atomicAdd(&out[(size_t)d * HDIM + col], acc[mt][nt][rr] * s);
                }
            }
        }
    }
}

// ---------------- pooling + head ----------------

__global__ void pool_kernel(const float* __restrict__ h, const int* __restrict__ batch,
                            const float* __restrict__ ws_w, const float* __restrict__ ws_b,
                            float* __restrict__ pooled) {
    int n = blockIdx.x, tid = threadIdx.x;
    float v = h[(size_t)n * HDIM + tid];
    float p = v * ws_w[tid];
    __shared__ float red[4];
    __shared__ float gate;
    for (int o = 32; o > 0; o >>= 1) p += __shfl_down(p, o, 64);
    if ((tid & 63) == 0) red[tid >> 6] = p;
    __syncthreads();
    if (tid == 0) {
        float s = red[0] + red[1] + red[2] + red[3] + ws_b[0];
        gate = 1.f / (1.f + __expf(-s));
    }
    __syncthreads();
    atomicAdd(&pooled[(size_t)batch[n] * HDIM + tid], gate * v);
}

__global__ void head_kernel(const float* __restrict__ pooled,
                            const float* __restrict__ w1, const float* __restrict__ b1,
                            const float* __restrict__ w2, const float* __restrict__ b2,
                            const float* __restrict__ w3, const float* __restrict__ b3,
                            float* __restrict__ out) {
    int b = blockIdx.x, tid = threadIdx.x;   // 64 threads = 1 wave
    __shared__ float sp[HDIM];
    __shared__ float m1[MDIM];
    __shared__ float m2[MDIM];
    for (int i = tid; i < HDIM; i += 64) sp[i] = pooled[(size_t)b * HDIM + i];
    __syncthreads();
    float a = b1[tid];
    for (int i = 0; i < HDIM; i++) a += sp[i] * w1[i * MDIM + tid];
    m1[tid] = a > 0.f ? a : 0.f;
    __syncthreads();
    float c = b2[tid];
    for (int i = 0; i < MDIM; i++) c += m1[i] * w2[i * MDIM + tid];
    m2[tid] = c > 0.f ? c : 0.f;
    __syncthreads();
    float p = m2[tid] * w3[tid];
    for (int o = 32; o > 0; o >>= 1) p += __shfl_down(p, o, 64);
    if (tid == 0) out[b] = p + b3[0];
}

// ---------------- launch ----------------

extern "C" void kernel_launch(void* const* d_in, const int* in_sizes, int n_in,
                              void* d_out, int out_size, void* d_ws, size_t ws_size,
                              hipStream_t stream) {
    const float* x     = (const float*)d_in[0];
    const int*   ei    = (const int*)d_in[1];
    const int*   et    = (const int*)d_in[2];
    const int*   batch = (const int*)d_in[3];
    const float* W1    = (const float*)d_in[4];
    const float* root1 = (const float*)d_in[5];
    const float* b1    = (const float*)d_in[6];
    const float* W2    = (const float*)d_in[7];
    const float* root2 = (const float*)d_in[8];
    const float* b2    = (const float*)d_in[9];
    const float* W3    = (const float*)d_in[10];
    const float* root3 = (const float*)d_in[11];
    const float* b3    = (const float*)d_in[12];
    const float* ws_w  = (const float*)d_in[13];
    const float* ws_b  = (const float*)d_in[14];
    const float* m_w1  = (const float*)d_in[15];
    const float* m_b1  = (const float*)d_in[16];
    const float* m_w2  = (const float*)d_in[17];
    const float* m_b2  = (const float*)d_in[18];
    const float* m_w3  = (const float*)d_in[19];
    const float* m_b3  = (const float*)d_in[20];
    float* out = (float*)d_out;

    char* ws = (char*)d_ws;
    size_t o = 0;
    auto take = [&](size_t bytes) { size_t r = o; o = (o + bytes + 255) & ~(size_t)255; return r; };

    const int EP = NEDGES + NNODES;     // edges incl. root pseudo-edges
    size_t o_cnt_rn = take((size_t)NREL * NNODES * 4);
    size_t o_tcnt   = take(RP * 4);
    size_t o_tcur   = take(RP * 4);
    size_t o_toff   = take((RP + 1) * 4);
    size_t o_esrc   = take((size_t)EP * 4);
    size_t o_edst   = take((size_t)EP * 4);
    size_t o_escale = take((size_t)EP * 4);
    size_t o_trel   = take(MAXT * 4);
    size_t o_tstart = take(MAXT * 4);
    size_t o_tnrows = take(MAXT * 4);
    size_t o_wt1    = take((size_t)RP * HDIM * FDIM * 2);
    size_t o_wt2    = take((size_t)RP * HDIM * HDIM * 2);
    size_t o_wt3    = take((size_t)RP * HDIM * HDIM * 2);
    size_t o_x16    = take((size_t)NNODES * FDIM * 2);
    size_t o_h16    = take((size_t)NNODES * HDIM * 2);
    size_t o_hf32   = take((size_t)NNODES * HDIM * 4);
    size_t o_pool   = take((size_t)NGRAPH * HDIM * 4);

    int*      cnt_rn   = (int*)(ws + o_cnt_rn);
    int*      type_cnt = (int*)(ws + o_tcnt);
    int*      type_cur = (int*)(ws + o_tcur);
    int*      type_off = (int*)(ws + o_toff);
    int*      esrc     = (int*)(ws + o_esrc);
    int*      edst     = (int*)(ws + o_edst);
    float*    escale   = (float*)(ws + o_escale);
    int*      trel     = (int*)(ws + o_trel);
    int*      tstart   = (int*)(ws + o_tstart);
    int*      tnrows   = (int*)(ws + o_tnrows);
    _Float16* Wt1      = (_Float16*)(ws + o_wt1);
    _Float16* Wt2      = (_Float16*)(ws + o_wt2);
    _Float16* Wt3      = (_Float16*)(ws + o_wt3);
    _Float16* x16      = (_Float16*)(ws + o_x16);
    _Float16* h16      = (_Float16*)(ws + o_h16);
    float*    hf32     = (float*)(ws + o_hf32);
    float*    pooled   = (float*)(ws + o_pool);

    // zero: cnt_rn + type_cnt + type_cur (contiguous), tile_nrows, pooled
    hipMemsetAsync(ws + o_cnt_rn, 0, o_toff - o_cnt_rn, stream);
    hipMemsetAsync(ws + o_tnrows, 0, MAXT * 4, stream);
    hipMemsetAsync(ws + o_pool, 0, (size_t)NGRAPH * HDIM * 4, stream);

    count_kernel<<<(NEDGES + 255) / 256, 256, 0, stream>>>(ei, et, cnt_rn, type_cnt);
    scan_tiles_kernel<<<1, 128, 0, stream>>>(type_cnt, type_off, trel, tstart, tnrows);
    scatter_kernel<<<(EP + 255) / 256, 256, 0, stream>>>(ei, et, cnt_rn, type_off, type_cur,
                                                         esrc, edst, escale);

    convW_kernel<<<dim3(RP, FDIM / 32, HDIM / 32), 256, 0, stream>>>(W1, root1, Wt1, FDIM);
    convW_kernel<<<dim3(RP, HDIM / 32, HDIM / 32), 256, 0, stream>>>(W2, root2, Wt2, HDIM);
    convW_kernel<<<dim3(RP, HDIM / 32, HDIM / 32), 256, 0, stream>>>(W3, root3, Wt3, HDIM);
    conv_x_kernel<<<(NNODES * FDIM + 255) / 256, 256, 0, stream>>>(x, x16);

    const int NH_BLK = (NNODES * HDIM + 255) / 256;

    // Layer 1 (K=64)
    bias_init_kernel<<<NH_BLK, 256, 0, stream>>>(b1, hf32);
    edge_gemm_kernel<FDIM><<<MAXT, 256, 0, stream>>>(x16, Wt1, esrc, edst, escale,
                                                     trel, tstart, tnrows, hf32);
    relu_kernel<<<NH_BLK, 256, 0, stream>>>(hf32, h16);

    // Layer 2 (K=256)
    bias_init_kernel<<<NH_BLK, 256, 0, stream>>>(b2, hf32);
    edge_gemm_kernel<HDIM><<<MAXT, 256, 0, stream>>>(h16, Wt2, esrc, edst, escale,
                                                     trel, tstart, tnrows, hf32);
    relu_kernel<<<NH_BLK, 256, 0, stream>>>(hf32, h16);

    // Layer 3 (K=256)
    bias_init_kernel<<<NH_BLK, 256, 0, stream>>>(b3, hf32);
    edge_gemm_kernel<HDIM><<<MAXT, 256, 0, stream>>>(h16, Wt3, esrc, edst, escale,
                                                     trel, tstart, tnrows, hf32);
    relu_kernel<<<NH_BLK, 256, 0, stream>>>(hf32, h16);

    pool_kernel<<<NNODES, 256, 0, stream>>>(hf32, batch, ws_w, ws_b, pooled);
    head_kernel<<<NGRAPH, 64, 0, stream>>>(pooled, m_w1, m_b1, m_w2, m_b2, m_w3, m_b3, out);

    (void)in_sizes; (void)n_in; (void)out_size; (void)ws_size;
}

// Round 3
// 491.178 us; speedup vs baseline: 2.6639x; 1.5665x over previous
//
#include <hip/hip_runtime.h>

// Problem constants (fixed by setup_inputs)
#define NNODES 8000
#define NEDGES 192000
#define NREL   65
#define RP     66      // +1 pseudo-relation for the root/self term
#define HDIM   256
#define FDIM   64
#define NGRAPH 128
#define MDIM   64
#define TILE_M 64
#define MAXT   3456    // >= E/64 + RP + N/64 = 3190
#define EPTOT  (NEDGES + NNODES)

typedef _Float16 half8 __attribute__((ext_vector_type(8)));
typedef _Float16 half4 __attribute__((ext_vector_type(4)));
typedef float    f32x4 __attribute__((ext_vector_type(4)));

// ---------------- setup kernels ----------------

// R1 lesson: never point >1000 atomics at one address. LDS-histogram the
// 65-bin type counts; dst-degree histogram (8000 addrs, ~24-way) is fine raw.
__global__ void count_kernel(const int* __restrict__ ei, const int* __restrict__ et,
                             int* __restrict__ cnt_rn, int* __restrict__ type_cnt,
                             int* __restrict__ ddeg) {
    __shared__ int lbin[NREL];
    int tid = threadIdx.x;
    if (tid < NREL) lbin[tid] = 0;
    __syncthreads();
    int e = blockIdx.x * 256 + tid;
    if (e < NEDGES) {
        int t = et[e];
        int d = ei[NEDGES + e];
        atomicAdd(&lbin[t], 1);
        atomicAdd(&cnt_rn[t * NNODES + d], 1);
        atomicAdd(&ddeg[d], 1);
    }
    __syncthreads();
    if (tid < NREL && lbin[tid] > 0) atomicAdd(&type_cnt[tid], lbin[tid]);
}

__global__ void scan_tiles_kernel(const int* __restrict__ type_cnt, int* __restrict__ type_off,
                                  int* __restrict__ tile_rel, int* __restrict__ tile_start,
                                  int* __restrict__ tile_nrows) {
    __shared__ int s_off[RP + 1];
    __shared__ int s_toff[RP + 1];
    if (threadIdx.x == 0) {
        int off = 0, toff = 0;
        for (int r = 0; r < RP; r++) {
            int c = (r < NREL) ? type_cnt[r] : NNODES;
            s_off[r] = off; s_toff[r] = toff;
            off += c; toff += (c + TILE_M - 1) / TILE_M;
        }
        s_off[RP] = off; s_toff[RP] = toff;
        type_off[RP] = off;
    }
    __syncthreads();
    int r = threadIdx.x;
    if (r < RP) {
        type_off[r] = s_off[r];
        int c = s_off[r + 1] - s_off[r];
        int nt = (c + TILE_M - 1) / TILE_M;
        for (int i = 0; i < nt; i++) {
            int idx = s_toff[r] + i;
            tile_rel[idx]   = r;
            tile_start[idx] = s_off[r] + i * TILE_M;
            tile_nrows[idx] = min(TILE_M, c - i * TILE_M);
        }
    }
}

// Exclusive prefix scan of (ddeg[n]+1) -> dst_off[0..NNODES]; +1 = root pseudo-edge.
__global__ void dst_scan_kernel(const int* __restrict__ ddeg, int* __restrict__ dst_off) {
    __shared__ int part[256];
    int t = threadIdx.x;
    int base = t * 32;
    int s = 0;
    for (int i = 0; i < 32; i++) {
        int n = base + i;
        if (n < NNODES) s += ddeg[n] + 1;
    }
    part[t] = s;
    __syncthreads();
    if (t == 0) {
        int run = 0;
        for (int i = 0; i < 256; i++) { int tmp = part[i]; part[i] = run; run += tmp; }
        dst_off[NNODES] = run;   // == EPTOT
    }
    __syncthreads();
    int run = part[t];
    for (int i = 0; i < 32; i++) {
        int n = base + i;
        if (n < NNODES) { dst_off[n] = run; run += ddeg[n] + 1; }
    }
}

// Relation-sorted slot p (block-aggregated rank) + dst-sorted output slot q.
__global__ void scatter_kernel(const int* __restrict__ ei, const int* __restrict__ et,
                               const int* __restrict__ cnt_rn, const int* __restrict__ type_off,
                               int* __restrict__ type_cur,
                               const int* __restrict__ dst_off, int* __restrict__ dst_cur,
                               int* __restrict__ esrc, int* __restrict__ eq,
                               float* __restrict__ escale) {
    __shared__ int lbin[NREL];
    __shared__ int gbase[NREL];
    int tid = threadIdx.x;
    if (tid < NREL) lbin[tid] = 0;
    __syncthreads();
    int i = blockIdx.x * 256 + tid;
    int t = 0, lrank = 0;
    bool is_edge = (i < NEDGES);
    if (is_edge) {
        t = et[i];
        lrank = atomicAdd(&lbin[t], 1);
    }
    __syncthreads();
    if (tid < NREL && lbin[tid] > 0) gbase[tid] = atomicAdd(&type_cur[tid], lbin[tid]);
    __syncthreads();
    if (is_edge) {
        int d = ei[NEDGES + i];
        int p = type_off[t] + gbase[t] + lrank;
        int q = dst_off[d] + atomicAdd(&dst_cur[d], 1);
        esrc[p] = ei[i];
        eq[p] = q;
        escale[p] = 1.0f / (float)cnt_rn[t * NNODES + d];
    } else if (i < EPTOT) {
        int n = i - NEDGES;
        int p = NEDGES + n;      // root pseudo-relation segment starts at E
        int q = dst_off[n] + atomicAdd(&dst_cur[n], 1);
        esrc[p] = n; eq[p] = q; escale[p] = 1.0f;
    }
}

// W [R][K][HDIM] fp32 (+ root [K][HDIM]) -> Wt [RP][HDIM][K] fp16 (transposed)
__global__ void convW_kernel(const float* __restrict__ W, const float* __restrict__ root,
                             _Float16* __restrict__ Wt, int K) {
    int r = blockIdx.x, k0 = blockIdx.y * 32, n0 = blockIdx.z * 32;
    const float* src = (r < NREL) ? (W + (size_t)r * K * HDIM) : root;
    __shared__ float tile[32][33];
    int tj = threadIdx.x & 31, ti = threadIdx.x >> 5;
    #pragma unroll
    for (int s = 0; s < 4; s++) {
        int i = ti + s * 8;
        tile[i][tj] = src[(size_t)(k0 + i) * HDIM + n0 + tj];
    }
    __syncthreads();
    #pragma unroll
    for (int s = 0; s < 4; s++) {
        int i = ti + s * 8;
        Wt[((size_t)r * HDIM + (n0 + i)) * K + k0 + tj] = (_Float16)tile[tj][i];
    }
}

__global__ void conv_x_kernel(const float* __restrict__ x, _Float16* __restrict__ x16) {
    int i = blockIdx.x * 256 + threadIdx.x;
    if (i < NNODES * FDIM) x16[i] = (_Float16)x[i];
}

// ---------------- phase 1: Y16[q] = scale * (h[src] @ W_r), plain stores ----------------
// Tile: 64 edges x 256 cols; 4 waves, wave w owns cols [w*64, w*64+64).
// Epilogue transposes through LDS (reusing the A buffer) for vectorized row stores.
template <int K>
__global__ __launch_bounds__(256)
void edge_gemm_kernel(const _Float16* __restrict__ hin, const _Float16* __restrict__ Wt,
                      const int* __restrict__ esrc, const int* __restrict__ eq,
                      const float* __restrict__ escale,
                      const int* __restrict__ tile_rel, const int* __restrict__ tile_start,
                      const int* __restrict__ tile_nrows,
                      _Float16* __restrict__ Y) {
    int nr = tile_nrows[blockIdx.x];
    if (nr == 0) return;
    int r  = tile_rel[blockIdx.x];
    int ts = tile_start[blockIdx.x];

    constexpr int LK = K + 8;            // A stride (fp16), +8 pad
    constexpr int SO = HDIM + 8;         // out stride (fp16) = 264
    constexpr int LMAX = (LK > SO) ? LK : SO;
    __shared__ _Float16 sbuf[TILE_M * LMAX];   // A tile, then reused for out tile
    __shared__ int   sq[TILE_M];
    __shared__ float sscale[TILE_M];

    int tid = threadIdx.x;
    constexpr int CPR = K / 8;           // 16B chunks per row
    for (int idx = tid; idx < TILE_M * CPR; idx += 256) {
        int row = idx / CPR, c = idx % CPR;
        uint4 v = make_uint4(0, 0, 0, 0);
        if (row < nr) {
            int src = esrc[ts + row];
            v = *(const uint4*)(hin + (size_t)src * K + c * 8);
        }
        *(uint4*)&sbuf[row * LK + c * 8] = v;
    }
    if (tid < TILE_M) {
        if (tid < nr) { sq[tid] = eq[ts + tid]; sscale[tid] = escale[ts + tid]; }
        else          { sq[tid] = 0;            sscale[tid] = 0.f; }
    }
    __syncthreads();

    int lane = tid & 63, w = tid >> 6;
    int lm = lane & 15, quad = lane >> 4;
    f32x4 acc[4][4] = {};
    const _Float16* Bbase = Wt + ((size_t)r * HDIM + w * 64 + lm) * K + quad * 8;
    const _Float16* Abase = sbuf + lm * LK + quad * 8;

    for (int kk = 0; kk < K; kk += 32) {
        half8 a[4], b[4];
        #pragma unroll
        for (int mt = 0; mt < 4; mt++)
            a[mt] = *(const half8*)(Abase + mt * 16 * LK + kk);
        #pragma unroll
        for (int nt = 0; nt < 4; nt++)
            b[nt] = *(const half8*)(Bbase + nt * 16 * K + kk);
        #pragma unroll
        for (int mt = 0; mt < 4; mt++)
            #pragma unroll
            for (int nt = 0; nt < 4; nt++)
                acc[mt][nt] = __builtin_amdgcn_mfma_f32_16x16x32_f16(a[mt], b[nt], acc[mt][nt], 0, 0, 0);
    }

    __syncthreads();   // all reads of the A tile complete before reuse as out tile

    // D[m][n]: m = mt*16 + quad*4 + rr, n = w*64 + nt*16 + lm
    #pragma unroll
    for (int mt = 0; mt < 4; mt++) {
        #pragma unroll
        for (int rr = 0; rr < 4; rr++) {
            int row = mt * 16 + quad * 4 + rr;
            float s = sscale[row];
            #pragma unroll
            for (int nt = 0; nt < 4; nt++) {
                int col = w * 64 + nt * 16 + lm;
                sbuf[row * SO + col] = (_Float16)(acc[mt][nt][rr] * s);
            }
        }
    }
    __syncthreads();

    // 64 rows x 512 B, vectorized: 2048 uint4 chunks over 256 threads
    for (int idx = tid; idx < TILE_M * 32; idx += 256) {
        int row = idx >> 5, seg = idx & 31;
        if (row < nr) {
            uint4 v = *(const uint4*)&sbuf[row * SO + seg * 8];
            *(uint4*)(Y + (size_t)sq[row] * HDIM + seg * 8) = v;
        }
    }
}

// ---------------- phase 2: CSR segment-reduce + bias + relu -> h16 ----------------
__global__ __launch_bounds__(256)
void reduce_kernel(const _Float16* __restrict__ Y, const int* __restrict__ dst_off,
                   const float* __restrict__ bias, _Float16* __restrict__ hout) {
    int n = blockIdx.x;
    int start = dst_off[n], end = dst_off[n + 1];
    int t = threadIdx.x;
    int c = t & 31;          // col group: 8 fp16
    int r = t >> 5;          // 8-way row parallelism
    float acc[8] = {0, 0, 0, 0, 0, 0, 0, 0};
    for (int j = start + r; j < end; j += 8) {
        half8 v = *(const half8*)(Y + (size_t)j * HDIM + c * 8);
        #pragma unroll
        for (int k = 0; k < 8; k++) acc[k] += (float)v[k];
    }
    __shared__ float red[8][32][8];
    #pragma unroll
    for (int k = 0; k < 8; k++) red[r][c][k] = acc[k];
    __syncthreads();
    if (t < 32) {
        float a[8];
        #pragma unroll
        for (int k = 0; k < 8; k++) a[k] = red[0][t][k];
        for (int rr = 1; rr < 8; rr++)
            #pragma unroll
            for (int k = 0; k < 8; k++) a[k] += red[rr][t][k];
        half8 o;
        #pragma unroll
        for (int k = 0; k < 8; k++) {
            float v = a[k] + bias[t * 8 + k];
            o[k] = (_Float16)(v > 0.f ? v : 0.f);
        }
        *(half8*)(hout + (size_t)n * HDIM + t * 8) = o;
    }
}

// ---------------- pooling + head (atomic-free) ----------------

// One wave per node: gate[n] = sigmoid(h[n] . ws_w + ws_b)
__global__ void gate_kernel(const _Float16* __restrict__ h, const float* __restrict__ ws_w,
                            const float* __restrict__ ws_b, float* __restrict__ gate) {
    int node = blockIdx.x * 4 + (threadIdx.x >> 6);
    int lane = threadIdx.x & 63;
    half4 v = *(const half4*)(h + (size_t)node * HDIM + lane * 4);
    float s = 0.f;
    #pragma unroll
    for (int k = 0; k < 4; k++) s += (float)v[k] * ws_w[lane * 4 + k];
    for (int o = 32; o > 0; o >>= 1) s += __shfl_down(s, o, 64);
    if (lane == 0) gate[node] = 1.f / (1.f + __expf(-(s + ws_b[0])));
}

// One block per graph; batch is sorted, so segments are contiguous (binary search).
__global__ void pool_kernel(const _Float16* __restrict__ h, const float* __restrict__ gate,
                            const int* __restrict__ batch, float* __restrict__ pooled) {
    int g = blockIdx.x, t = threadIdx.x;
    int a = 0, b = NNODES;
    while (a < b) { int m = (a + b) >> 1; if (batch[m] < g) a = m + 1; else b = m; }
    int lo = a;
    b = NNODES;
    while (a < b) { int m = (a + b) >> 1; if (batch[m] < g + 1) a = m + 1; else b = m; }
    int hi = a;
    float acc = 0.f;
    for (int n = lo; n < hi; n++)
        acc += gate[n] * (float)h[(size_t)n * HDIM + t];
    pooled[(size_t)g * HDIM + t] = acc;
}

__global__ void head_kernel(const float* __restrict__ pooled,
                            const float* __restrict__ w1, const float* __restrict__ b1,
                            const float* __restrict__ w2, const float* __restrict__ b2,
                            const float* __restrict__ w3, const float* __restrict__ b3,
                            float* __restrict__ out) {
    int b = blockIdx.x, tid = threadIdx.x;   // 64 threads = 1 wave
    __shared__ float sp[HDIM];
    __shared__ float m1[MDIM];
    __shared__ float m2[MDIM];
    for (int i = tid; i < HDIM; i += 64) sp[i] = pooled[(size_t)b * HDIM + i];
    __syncthreads();
    float a = b1[tid];
    for (int i = 0; i < HDIM; i++) a += sp[i] * w1[i * MDIM + tid];
    m1[tid] = a > 0.f ? a : 0.f;
    __syncthreads();
    float c = b2[tid];
    for (int i = 0; i < MDIM; i++) c += m1[i] * w2[i * MDIM + tid];
    m2[tid] = c > 0.f ? c : 0.f;
    __syncthreads();
    float p = m2[tid] * w3[tid];
    for (int o = 32; o > 0; o >>= 1) p += __shfl_down(p, o, 64);
    if (tid == 0) out[b] = p + b3[0];
}

// ---------------- launch ----------------

extern "C" void kernel_launch(void* const* d_in, const int* in_sizes, int n_in,
                              void* d_out, int out_size, void* d_ws, size_t ws_size,
                              hipStream_t stream) {
    const float* x     = (const float*)d_in[0];
    const int*   ei    = (const int*)d_in[1];
    const int*   et    = (const int*)d_in[2];
    const int*   batch = (const int*)d_in[3];
    const float* W1    = (const float*)d_in[4];
    const float* root1 = (const float*)d_in[5];
    const float* b1    = (const float*)d_in[6];
    const float* W2    = (const float*)d_in[7];
    const float* root2 = (const float*)d_in[8];
    const float* b2    = (const float*)d_in[9];
    const float* W3    = (const float*)d_in[10];
    const float* root3 = (const float*)d_in[11];
    const float* b3    = (const float*)d_in[12];
    const float* ws_w  = (const float*)d_in[13];
    const float* ws_b  = (const float*)d_in[14];
    const float* m_w1  = (const float*)d_in[15];
    const float* m_b1  = (const float*)d_in[16];
    const float* m_w2  = (const float*)d_in[17];
    const float* m_b2  = (const float*)d_in[18];
    const float* m_w3  = (const float*)d_in[19];
    const float* m_b3  = (const float*)d_in[20];
    float* out = (float*)d_out;

    char* ws = (char*)d_ws;
    size_t o = 0;
    auto take = [&](size_t bytes) { size_t r = o; o = (o + bytes + 255) & ~(size_t)255; return r; };

    size_t o_cnt_rn = take((size_t)NREL * NNODES * 4);
    size_t o_tcnt   = take(RP * 4);
    size_t o_tcur   = take(RP * 4);
    size_t o_toff   = take((RP + 1) * 4);
    size_t o_ddeg   = take((size_t)NNODES * 4);
    size_t o_dcur   = take((size_t)NNODES * 4);
    size_t o_doff   = take((size_t)(NNODES + 1) * 4);
    size_t o_esrc   = take((size_t)EPTOT * 4);
    size_t o_eq     = take((size_t)EPTOT * 4);
    size_t o_escale = take((size_t)EPTOT * 4);
    size_t o_trel   = take(MAXT * 4);
    size_t o_tstart = take(MAXT * 4);
    size_t o_tnrows = take(MAXT * 4);
    size_t o_wt1    = take((size_t)RP * HDIM * FDIM * 2);
    size_t o_wt2    = take((size_t)RP * HDIM * HDIM * 2);
    size_t o_wt3    = take((size_t)RP * HDIM * HDIM * 2);
    size_t o_x16    = take((size_t)NNODES * FDIM * 2);
    size_t o_h16    = take((size_t)NNODES * HDIM * 2);
    size_t o_gate   = take((size_t)NNODES * 4);
    size_t o_pool   = take((size_t)NGRAPH * HDIM * 4);
    size_t o_y16    = take((size_t)EPTOT * HDIM * 2);   // 102.4 MB

    int*      cnt_rn   = (int*)(ws + o_cnt_rn);
    int*      type_cnt = (int*)(ws + o_tcnt);
    int*      type_cur = (int*)(ws + o_tcur);
    int*      type_off = (int*)(ws + o_toff);
    int*      ddeg     = (int*)(ws + o_ddeg);
    int*      dst_cur  = (int*)(ws + o_dcur);
    int*      dst_off  = (int*)(ws + o_doff);
    int*      esrc     = (int*)(ws + o_esrc);
    int*      eq       = (int*)(ws + o_eq);
    float*    escale   = (float*)(ws + o_escale);
    int*      trel     = (int*)(ws + o_trel);
    int*      tstart   = (int*)(ws + o_tstart);
    int*      tnrows   = (int*)(ws + o_tnrows);
    _Float16* Wt1      = (_Float16*)(ws + o_wt1);
    _Float16* Wt2      = (_Float16*)(ws + o_wt2);
    _Float16* Wt3      = (_Float16*)(ws + o_wt3);
    _Float16* x16      = (_Float16*)(ws + o_x16);
    _Float16* h16      = (_Float16*)(ws + o_h16);
    float*    gate     = (float*)(ws + o_gate);
    float*    pooled   = (float*)(ws + o_pool);
    _Float16* Y16      = (_Float16*)(ws + o_y16);

    // zero: cnt_rn + type_cnt + type_cur (contiguous); ddeg + dst_cur (contiguous); tile_nrows
    hipMemsetAsync(ws + o_cnt_rn, 0, o_toff - o_cnt_rn, stream);
    hipMemsetAsync(ws + o_ddeg, 0, o_doff - o_ddeg, stream);
    hipMemsetAsync(ws + o_tnrows, 0, MAXT * 4, stream);

    count_kernel<<<(NEDGES + 255) / 256, 256, 0, stream>>>(ei, et, cnt_rn, type_cnt, ddeg);
    scan_tiles_kernel<<<1, 128, 0, stream>>>(type_cnt, type_off, trel, tstart, tnrows);
    dst_scan_kernel<<<1, 256, 0, stream>>>(ddeg, dst_off);
    scatter_kernel<<<(EPTOT + 255) / 256, 256, 0, stream>>>(ei, et, cnt_rn, type_off, type_cur,
                                                            dst_off, dst_cur, esrc, eq, escale);

    convW_kernel<<<dim3(RP, FDIM / 32, HDIM / 32), 256, 0, stream>>>(W1, root1, Wt1, FDIM);
    convW_kernel<<<dim3(RP, HDIM / 32, HDIM / 32), 256, 0, stream>>>(W2, root2, Wt2, HDIM);
    convW_kernel<<<dim3(RP, HDIM / 32, HDIM / 32), 256, 0, stream>>>(W3, root3, Wt3, HDIM);
    conv_x_kernel<<<(NNODES * FDIM + 255) / 256, 256, 0, stream>>>(x, x16);

    // Layer 1 (K=64)
    edge_gemm_kernel<FDIM><<<MAXT, 256, 0, stream>>>(x16, Wt1, esrc, eq, escale,
                                                     trel, tstart, tnrows, Y16);
    reduce_kernel<<<NNODES, 256, 0, stream>>>(Y16, dst_off, b1, h16);

    // Layer 2 (K=256)
    edge_gemm_kernel<HDIM><<<MAXT, 256, 0, stream>>>(h16, Wt2, esrc, eq, escale,
                                                     trel, tstart, tnrows, Y16);
    reduce_kernel<<<NNODES, 256, 0, stream>>>(Y16, dst_off, b2, h16);

    // Layer 3 (K=256)
    edge_gemm_kernel<HDIM><<<MAXT, 256, 0, stream>>>(h16, Wt3, esrc, eq, escale,
                                                     trel, tstart, tnrows, Y16);
    reduce_kernel<<<NNODES, 256, 0, stream>>>(Y16, dst_off, b3, h16);

    gate_kernel<<<NNODES / 4, 256, 0, stream>>>(h16, ws_w, ws_b, gate);
    pool_kernel<<<NGRAPH, 256, 0, stream>>>(h16, gate, batch, pooled);
    head_kernel<<<NGRAPH, 64, 0, stream>>>(pooled, m_w1, m_b1, m_w2, m_b2, m_w3, m_b3, out);

    (void)in_sizes; (void)n_in; (void)out_size; (void)ws_size;
}